// Round 2
// baseline (553.126 us; speedup 1.0000x reference)
//
#include <hip/hip_runtime.h>

// ---------------------------------------------------------------------------
// TimeSeriesTransformer: X[128,256,128] -> qkv -> softmax(K Q^T) V -> MLP
// R2: GEMMs load B fp32 directly into B-fragment registers (no LDS stage, no
// bank conflicts, no redundant cross-wave reads; waves split N). proj writes
// vT via LDS transpose (16 B stores). Reduces fully unrolled + vectorized.
// ---------------------------------------------------------------------------

#define DI __device__ __forceinline__

typedef __attribute__((ext_vector_type(4))) float f32x4;
typedef __attribute__((ext_vector_type(8))) short bf16x8;

DI unsigned short f2bf(float f) {      // fp32 -> bf16, round-to-nearest-even
  unsigned int u = __float_as_uint(f);
  u += 0x7fffu + ((u >> 16) & 1u);
  return (unsigned short)(u >> 16);
}

// ---- prep: transpose Qw/Kw/Vw (fp32 [ni][no]) -> bf16 wT [3][no][ni] -------
__global__ __launch_bounds__(256) void prep_wt(const float* __restrict__ Qw,
                                               const float* __restrict__ Kw,
                                               const float* __restrict__ Vw,
                                               unsigned short* __restrict__ wT) {
  int gid = blockIdx.x * 256 + threadIdx.x;   // 0..49151
  int w  = gid >> 14;
  int j  = gid & 16383;
  int no = j >> 7, ni = j & 127;
  const float* src = (w == 0) ? Qw : (w == 1) ? Kw : Vw;
  wT[gid] = f2bf(src[ni * 128 + no]);
}

// ---- projections: q,k row-major bf16 [B*T][128]; v transposed [B][128][256]
__global__ __launch_bounds__(256) void proj_kernel(
    const float* __restrict__ X, const unsigned short* __restrict__ wT,
    const float* __restrict__ Qb, const float* __restrict__ Kb,
    const float* __restrict__ Vb,
    unsigned short* __restrict__ q_ws, unsigned short* __restrict__ k_ws,
    unsigned short* __restrict__ vT_ws) {
  __shared__ __align__(16) unsigned short vtile[64 * 128];   // 16 KB
  int wv = threadIdx.x >> 6, lane = threadIdx.x & 63;
  int quad = lane >> 4, l15 = lane & 15;
  int R0blk = blockIdx.x * 64;
  int R0 = R0blk + wv * 16;                  // 16-row tile per wave

  // A-fragments of X (shared by all 3 projections): A[m=l15][k=quad*8+j]
  bf16x8 af[4];
  const float* xbase = X + (size_t)(R0 + l15) * 128 + quad * 8;
#pragma unroll
  for (int kc = 0; kc < 4; ++kc) {
    f32x4 x0 = *(const f32x4*)(xbase + kc * 32);
    f32x4 x1 = *(const f32x4*)(xbase + kc * 32 + 4);
    bf16x8 a;
#pragma unroll
    for (int j = 0; j < 4; ++j) { a[j] = (short)f2bf(x0[j]); a[4 + j] = (short)f2bf(x1[j]); }
    af[kc] = a;
  }

#pragma unroll
  for (int p = 0; p < 3; ++p) {
    const unsigned short* wt = wT + p * 16384;
    const float* bias = (p == 0) ? Qb : (p == 1) ? Kb : Vb;
#pragma unroll
    for (int nt = 0; nt < 8; ++nt) {
      f32x4 acc = {0.f, 0.f, 0.f, 0.f};
#pragma unroll
      for (int kc = 0; kc < 4; ++kc) {
        bf16x8 b = *(const bf16x8*)(wt + (size_t)(nt * 16 + l15) * 128 + kc * 32 + quad * 8);
        acc = __builtin_amdgcn_mfma_f32_16x16x32_bf16(af[kc], b, acc, 0, 0, 0);
      }
      int no = nt * 16 + l15;
      float bv = bias[no];
#pragma unroll
      for (int r4 = 0; r4 < 4; ++r4) {          // C/D: col=l15, row=quad*4+r4
        unsigned short val = f2bf(acc[r4] + bv);
        int rowLoc = wv * 16 + quad * 4 + r4;
        int row = R0blk + rowLoc;
        if (p == 0)      q_ws[(size_t)row * 128 + no] = val;
        else if (p == 1) k_ws[(size_t)row * 128 + no] = val;
        else             vtile[rowLoc * 128 + no] = val;
      }
    }
  }
  __syncthreads();
  // transposed v write: vT[b][no][t], 32 shorts (64 B) per thread, 16 B stores
  {
    int no = threadIdx.x >> 1;
    int th = (threadIdx.x & 1) * 32;
    int bb = R0blk >> 8;
    int tBase = (R0blk & 255) + th;
    unsigned short* dst = vT_ws + ((size_t)bb * 128 + no) * 256 + tBase;
#pragma unroll
    for (int g = 0; g < 4; ++g) {
      bf16x8 v8;
#pragma unroll
      for (int i = 0; i < 8; ++i) v8[i] = (short)vtile[(th + g * 8 + i) * 128 + no];
      *(bf16x8*)(dst + g * 8) = v8;
    }
  }
}

// ---- attention: per block 64 t-rows of one batch; wave = 16-row tile -------
__global__ __launch_bounds__(256) void attn_kernel(
    const unsigned short* __restrict__ q_ws, const unsigned short* __restrict__ k_ws,
    const unsigned short* __restrict__ vT_ws, unsigned short* __restrict__ r_ws) {
  __shared__ __align__(16) unsigned short p_lds[4][16 * 264];  // pad 264 vs 256
  int wv = threadIdx.x >> 6, lane = threadIdx.x & 63;
  int quad = lane >> 4, l15 = lane & 15;
  int b  = blockIdx.x >> 2;
  int t0 = (blockIdx.x & 3) * 64 + wv * 16;

  // K A-fragments (16 rows of k)
  bf16x8 kf[4];
  const unsigned short* kbase = k_ws + ((size_t)b * 256 + t0 + l15) * 128 + quad * 8;
#pragma unroll
  for (int kc = 0; kc < 4; ++kc) kf[kc] = *(const bf16x8*)(kbase + kc * 32);

  // scores S[16][256]: S[t][s] = k[t]·q[s]
  f32x4 sc[16];
#pragma unroll
  for (int st = 0; st < 16; ++st) {
    f32x4 acc = {0.f, 0.f, 0.f, 0.f};
    const unsigned short* qbase = q_ws + ((size_t)b * 256 + st * 16 + l15) * 128 + quad * 8;
#pragma unroll
    for (int kc = 0; kc < 4; ++kc) {
      bf16x8 qf = *(const bf16x8*)(qbase + kc * 32);   // B[k=kk][n=s]
      acc = __builtin_amdgcn_mfma_f32_16x16x32_bf16(kf[kc], qf, acc, 0, 0, 0);
    }
    sc[st] = acc;
  }

  // softmax over s (row = quad*4+r4, held by 16-lane row group)
  float inv[4];
#pragma unroll
  for (int r4 = 0; r4 < 4; ++r4) {
    float m = sc[0][r4];
#pragma unroll
    for (int st = 1; st < 16; ++st) m = fmaxf(m, sc[st][r4]);
#pragma unroll
    for (int d = 1; d < 16; d <<= 1) m = fmaxf(m, __shfl_xor(m, d, 64));
    float s = 0.f;
#pragma unroll
    for (int st = 0; st < 16; ++st) { float e = __expf(sc[st][r4] - m); sc[st][r4] = e; s += e; }
#pragma unroll
    for (int d = 1; d < 16; d <<= 1) s += __shfl_xor(s, d, 64);
    inv[r4] = 1.f / s;
  }

  // P (C-layout) -> LDS so it can re-enter MFMA in A-layout
#pragma unroll
  for (int st = 0; st < 16; ++st)
#pragma unroll
    for (int r4 = 0; r4 < 4; ++r4)
      p_lds[wv][(quad * 4 + r4) * 264 + st * 16 + l15] = f2bf(sc[st][r4] * inv[r4]);
  __syncthreads();

  // r = P @ V  (B-frags from vT: B[k=s][n=vv] = vT[vv][s])
  const unsigned short* pbase = &p_lds[wv][l15 * 264 + quad * 8];
#pragma unroll
  for (int vt = 0; vt < 8; ++vt) {
    f32x4 acc = {0.f, 0.f, 0.f, 0.f};
    const unsigned short* vbase = vT_ws + ((size_t)b * 128 + vt * 16 + l15) * 256 + quad * 8;
#pragma unroll
    for (int s8 = 0; s8 < 8; ++s8) {
      bf16x8 pf = *(const bf16x8*)(pbase + s8 * 32);
      bf16x8 vf = *(const bf16x8*)(vbase + s8 * 32);
      acc = __builtin_amdgcn_mfma_f32_16x16x32_bf16(pf, vf, acc, 0, 0, 0);
    }
#pragma unroll
    for (int r4 = 0; r4 < 4; ++r4)
      r_ws[((size_t)b * 256 + t0 + quad * 4 + r4) * 128 + vt * 16 + l15] = f2bf(acc[r4]);
  }
}

// ---- K-split GEMM, register-direct B path ----------------------------------
// A bf16 [128 x Ktot] (lda). B fp32 [Ktot x N] (ldb). Waves split N: each
// wave computes all 128 M-rows x 32 N-cols. B loaded straight into fragment
// regs (dword/lane, 64 B row segments), 1-chunk register double-buffer.
__global__ __launch_bounds__(256) void gemm_ks(
    const unsigned short* __restrict__ A, int lda,
    const float* __restrict__ B, int ldb,
    float* __restrict__ slab, int ldo, int nChunks) {
  int wv = threadIdx.x >> 6, lane = threadIdx.x & 63;
  int quad = lane >> 4, l15 = lane & 15;
  int n0 = blockIdx.x * 128 + wv * 32;
  size_t k0 = (size_t)blockIdx.y * nChunks * 32;

  f32x4 acc[8][2];
#pragma unroll
  for (int mt = 0; mt < 8; ++mt)
#pragma unroll
    for (int nt = 0; nt < 2; ++nt) acc[mt][nt] = (f32x4){0.f, 0.f, 0.f, 0.f};

  const float* bbase = B + (k0 + quad * 8) * (size_t)ldb + n0 + l15;
  const unsigned short* abase = A + (size_t)l15 * lda + k0 + quad * 8;

  float bn[2][8];
  bf16x8 an[8];
#pragma unroll
  for (int nt = 0; nt < 2; ++nt)
#pragma unroll
    for (int j = 0; j < 8; ++j) bn[nt][j] = bbase[(size_t)j * ldb + nt * 16];
#pragma unroll
  for (int mt = 0; mt < 8; ++mt) an[mt] = *(const bf16x8*)(abase + (size_t)mt * 16 * lda);

  for (int c = 0; c < nChunks; ++c) {
    float bc[2][8];
    bf16x8 ac[8];
#pragma unroll
    for (int nt = 0; nt < 2; ++nt)
#pragma unroll
      for (int j = 0; j < 8; ++j) bc[nt][j] = bn[nt][j];
#pragma unroll
    for (int mt = 0; mt < 8; ++mt) ac[mt] = an[mt];

    if (c + 1 < nChunks) {                       // prefetch next chunk
      const float* b2 = bbase + (size_t)(c + 1) * 32 * ldb;
      const unsigned short* a2 = abase + (size_t)(c + 1) * 32;
#pragma unroll
      for (int nt = 0; nt < 2; ++nt)
#pragma unroll
        for (int j = 0; j < 8; ++j) bn[nt][j] = b2[(size_t)j * ldb + nt * 16];
#pragma unroll
      for (int mt = 0; mt < 8; ++mt) an[mt] = *(const bf16x8*)(a2 + (size_t)mt * 16 * lda);
    }

    bf16x8 bF[2];
#pragma unroll
    for (int nt = 0; nt < 2; ++nt)
#pragma unroll
      for (int j = 0; j < 8; ++j) bF[nt][j] = (short)f2bf(bc[nt][j]);
#pragma unroll
    for (int mt = 0; mt < 8; ++mt)
#pragma unroll
      for (int nt = 0; nt < 2; ++nt)
        acc[mt][nt] = __builtin_amdgcn_mfma_f32_16x16x32_bf16(ac[mt], bF[nt], acc[mt][nt], 0, 0, 0);
  }

  float* out = slab + (size_t)blockIdx.y * (size_t)ldo * 128;
#pragma unroll
  for (int mt = 0; mt < 8; ++mt)
#pragma unroll
    for (int nt = 0; nt < 2; ++nt)
#pragma unroll
      for (int r4 = 0; r4 < 4; ++r4)
        out[(size_t)(mt * 16 + quad * 4 + r4) * ldo + n0 + nt * 16 + l15] = acc[mt][nt][r4];
}

// ---- slab reduce + bias (+ optional sigmoid->bf16), f32x4 per thread -------
template <int NS, int SIG>
__global__ __launch_bounds__(256) void reduce_k(
    const float* __restrict__ slabs, int slabStride,
    const float* __restrict__ bias, int biasMask, void* __restrict__ outp) {
  int gid = blockIdx.x * 256 + threadIdx.x;
  int e = gid * 4;
  f32x4 s = {0.f, 0.f, 0.f, 0.f};
#pragma unroll
  for (int y = 0; y < NS; ++y) {
    f32x4 v = *(const f32x4*)(slabs + (size_t)y * slabStride + e);
    s.x += v.x; s.y += v.y; s.z += v.z; s.w += v.w;
  }
  f32x4 bv = *(const f32x4*)(bias + (e & biasMask));
  s.x += bv.x; s.y += bv.y; s.z += bv.z; s.w += bv.w;
  if (SIG) {
    unsigned long long pk = 0;
#pragma unroll
    for (int j = 0; j < 4; ++j) {
      float sv = (j == 0) ? s.x : (j == 1) ? s.y : (j == 2) ? s.z : s.w;
      pk |= (unsigned long long)f2bf(1.f / (1.f + __expf(-sv))) << (16 * j);
    }
    *(unsigned long long*)((unsigned short*)outp + e) = pk;
  } else {
    *(f32x4*)((float*)outp + e) = s;
  }
}

// ---------------------------------------------------------------------------
extern "C" void kernel_launch(void* const* d_in, const int* in_sizes, int n_in,
                              void* d_out, int out_size, void* d_ws, size_t ws_size,
                              hipStream_t stream) {
  const float* X  = (const float*)d_in[0];
  const float* Qw = (const float*)d_in[1];
  const float* Qb = (const float*)d_in[2];
  const float* Kw = (const float*)d_in[3];
  const float* Kb = (const float*)d_in[4];
  const float* Vw = (const float*)d_in[5];
  const float* Vb = (const float*)d_in[6];
  const float* W1 = (const float*)d_in[7];
  const float* b1 = (const float*)d_in[8];
  const float* W2 = (const float*)d_in[9];
  const float* b2 = (const float*)d_in[10];
  const float* W3 = (const float*)d_in[11];
  const float* b3 = (const float*)d_in[12];

  // workspace layout (bytes), total ~136 MB (ws is 1 GiB)
  char* ws = (char*)d_ws;
  unsigned short* wT    = (unsigned short*)(ws + 0);          //  96 KB
  unsigned short* q_ws  = (unsigned short*)(ws + 98304);      // 8.39 MB
  unsigned short* k_ws  = (unsigned short*)(ws + 8486912);    // 8.39 MB
  unsigned short* vT_ws = (unsigned short*)(ws + 16875520);   // 8.39 MB
  unsigned short* r_ws  = (unsigned short*)(ws + 25264128);   // 8.39 MB
  float* g1            = (float*)(ws + 33652736);             // 32 MB
  unsigned short* h1bf = (unsigned short*)(ws + 67207168);    // 0.5 MB
  float* g2            = (float*)(ws + 67731456);             // 32 MB
  unsigned short* h2bf = (unsigned short*)(ws + 101285888);   // 0.5 MB
  float* g3            = (float*)(ws + 101810176);            // 32 MB

  prep_wt<<<192, 256, 0, stream>>>(Qw, Kw, Vw, wT);
  proj_kernel<<<512, 256, 0, stream>>>(X, wT, Qb, Kb, Vb, q_ws, k_ws, vT_ws);
  attn_kernel<<<512, 256, 0, stream>>>(q_ws, k_ws, vT_ws, r_ws);
  // h1pre = r @ W1 : K=32768 split 32 ways (512 blocks, 2/CU)
  gemm_ks<<<dim3(16, 32), 256, 0, stream>>>(r_ws, 32768, W1, 2048, g1, 2048, 32);
  reduce_k<32, 1><<<256, 256, 0, stream>>>(g1, 262144, b1, 2047, h1bf);
  // h2pre = h1 @ W2 : K=2048 split 32 ways (512 blocks)
  gemm_ks<<<dim3(16, 32), 256, 0, stream>>>(h1bf, 2048, W2, 2048, g2, 2048, 2);
  reduce_k<32, 1><<<256, 256, 0, stream>>>(g2, 262144, b2, 2047, h2bf);
  // out = h2 @ W3 : K=2048 split 16 ways, N=4096 (512 blocks)
  gemm_ks<<<dim3(32, 16), 256, 0, stream>>>(h2bf, 2048, W3, 4096, g3, 4096, 4);
  reduce_k<16, 0><<<512, 256, 0, stream>>>(g3, 524288, b3, 4095, (float*)d_out);
}